// Round 8
// baseline (232.866 us; speedup 1.0000x reference)
//
#include <hip/hip_runtime.h>
#include <hip/hip_bf16.h>
#include <cstdint>
#include <cstddef>

typedef __hip_bfloat16 bf16;
typedef __attribute__((ext_vector_type(8))) short s16x8;
typedef __attribute__((ext_vector_type(4))) float f32x4;

#define MAXN 100
#define HH   4
#define FIN  128
#define KS1  25
#define GLDK 136

static inline int ceil_div(int a, int b){ return (a + b - 1) / b; }

__device__ inline short f2bf(float f){               // RNE float->bf16 bits
  unsigned int u = __float_as_uint(f);
  u = (u + 0x7FFF + ((u >> 16) & 1)) >> 16;
  return (short)u;
}
__device__ inline float loadf(const void* s, size_t i, bool isbf){
  return isbf ? __bfloat162float(((const bf16*)s)[i]) : ((const float*)s)[i];
}
// per-block dtype sniff: wave-0 lanes sample x's even half-words; bf16 data decodes
// sane ~100%, f32 low-halves ~11% -> popcount threshold 32 of 64.
__device__ inline bool block_sniff(const void* x, int tid, int* flagS){
  if (tid < 64){
    unsigned short b = ((const unsigned short*)x)[2 * tid];
    float v = __uint_as_float(((unsigned)b) << 16);
    float a = fabsf(v);
    bool ok = (a >= 6.1e-5f && a <= 16384.f);
    unsigned long long m = __ballot(ok);
    if (tid == 0) *flagS = (__popcll(m) >= 32) ? 1 : 0;
  }
  __syncthreads();
  return *flagS != 0;
}

// ---------------- unified prep: casts + TILED transposes + fills, flat 1-D grid ----------------
// wprep path rewritten as 64x64 LDS tile transpose: coalesced source reads (lanes along n),
// stage in T[64][66] (stride-66 shorts -> 2-way-free reads), 128B-contiguous dest writes.
// All transpose shapes are multiples of 64 (128/256). Same f2bf(loadf) per element -> bit-identical.
struct PrepBatch {
  const void* src[40];
  void*       dst[40];
  int         a[40];
  int         b[40];     // 0: cast, >0: wprep N, -1: fill 0, -2: fill 1
  int         blk0[41];
  int         ne;
  const void* xptr;      // for inline sniff
};

__global__ __launch_bounds__(256) void prep_all(PrepBatch pb){
  __shared__ int flagS;
  __shared__ short T[64][66];
  int tid = threadIdx.x;
  bool isbf = block_sniff(pb.xptr, tid, &flagS);
  int blk = blockIdx.x;
  int t = 0;
  while (t + 1 < pb.ne && pb.blk0[t + 1] <= blk) t++;
  int local = blk - pb.blk0[t];
  const void* s = pb.src[t];
  int bt = pb.b[t];
  if (bt < 0){
    float val = (bt == -2) ? 1.0f : 0.0f;
    int n = pb.a[t];
    float* d = (float*)pb.dst[t];
    int v = local * 256 + tid;
    int base = v * 4;
    if (base + 3 < n) ((float4*)d)[v] = make_float4(val, val, val, val);
    else for (int j = base; j < n && j < base + 4; j++) d[j] = val;
  } else if (bt == 0){
    int n = pb.a[t];
    float* d = (float*)pb.dst[t];
    int v = local * 256 + tid;
    int base = v * 4;
    if (base + 3 < n){
      float4 f;
      if (isbf){
        ushort4 u = ((const ushort4*)s)[v];
        f.x = __uint_as_float(((unsigned)u.x) << 16);
        f.y = __uint_as_float(((unsigned)u.y) << 16);
        f.z = __uint_as_float(((unsigned)u.z) << 16);
        f.w = __uint_as_float(((unsigned)u.w) << 16);
      } else f = ((const float4*)s)[v];
      ((float4*)d)[v] = f;
    } else {
      for (int j = base; j < n && j < base + 4; j++) d[j] = loadf(s, j, isbf);
    }
  } else {
    // tiled transpose: source W[K][Nn] row-major -> dest WT[Nn][ldt=K+8] bf16
    int K = pb.a[t], Nn = bt, ldt = K + 8;
    short* d = (short*)pb.dst[t];
    int tilesN = Nn >> 6;
    int tk = local / tilesN, tn = local - tk * tilesN;
    int k0 = tk << 6, n0 = tn << 6;
    int r = tid >> 6, c = tid & 63;
#pragma unroll
    for (int i = 0; i < 16; i++){
      int lk = r * 16 + i;
      T[lk][c] = f2bf(loadf(s, (size_t)(k0 + lk) * Nn + n0 + c, isbf));
    }
    __syncthreads();
#pragma unroll
    for (int i = 0; i < 16; i++){
      int ln = r * 16 + i;
      d[(size_t)(n0 + ln) * ldt + k0 + c] = T[c][ln];
    }
  }
}

// ---------------- adjacency count: cnt[g][dl][sl] += 1 per edge (exact in fp32) ----------------
__global__ __launch_bounds__(256) void adj_cnt(const int* __restrict__ src, const int* __restrict__ dst,
                                               float* __restrict__ A, int e){
  int i = blockIdx.x * 256 + threadIdx.x;
  if (i >= e) return;
  int s = src[i], d = dst[i];
  int g = d / MAXN;
  int dl = d - g * MAXN;
  int sl = s - (s / MAXN) * MAXN;
  atomicAdd(&A[(size_t)g * (MAXN * MAXN) + dl * MAXN + sl], 1.0f);
}

// ---------------- ubar_q0: 4-way k-split Q0 + float4 Ubar row ----------------
__global__ __launch_bounds__(256) void ubar_q0(const float* __restrict__ S0,
    const float* __restrict__ Wq0, const float* __restrict__ bq0,
    const float* __restrict__ Wk0, const float* __restrict__ bk0,
    float* __restrict__ Q0, short* __restrict__ Ubart, float* __restrict__ cvec)
{
  __shared__ float part[256];
  __shared__ float q0s[64];
  int j = blockIdx.x, h = j / 25, q = j - h * 25;
  int tid = threadIdx.x;
  // Q0 slice via 4-way k-split (all 256 threads active)
  {
    int c = tid & 63, kq = tid >> 6;
    const float* s0 = S0 + q * 256 + kq * 64;
    const float* wq = Wq0 + (size_t)(kq * 64) * 256 + h * 64 + c;
    float a = 0.f;
#pragma unroll
    for (int e = 0; e < 64; e++) a = fmaf(s0[e], wq[(size_t)e * 256], a);
    part[kq * 64 + c] = a;
  }
  __syncthreads();
  if (tid < 64){
    int c = h * 64 + tid;
    float acc = bq0[c] + part[tid] + part[64 + tid] + part[128 + tid] + part[192 + tid];
    q0s[tid] = acc;
    Q0[q * 256 + c] = acc;
  }
  __syncthreads();
  float acc = 0.f;
  const float* wp = &Wk0[(size_t)tid * 256 + h * 64];
#pragma unroll
  for (int d = 0; d < 64; d += 4){
    float4 w4 = *reinterpret_cast<const float4*>(wp + d);
    float4 q4 = *reinterpret_cast<const float4*>(&q0s[d]);
    acc = fmaf(w4.x, q4.x, acc); acc = fmaf(w4.y, q4.y, acc);
    acc = fmaf(w4.z, q4.z, acc); acc = fmaf(w4.w, q4.w, acc);
  }
  Ubart[(size_t)j * 264 + tid] = f2bf(acc * 0.0625f);
  if (tid == 0){
    float cb = 0.f;
    for (int d = 0; d < 64; d++) cb = fmaf(bk0[h * 64 + d], q0s[d], cb);
    cvec[j] = cb * 0.0625f;
  }
}

// ---------------- gcn_tail: GCN + fused VdS-GEMM + attention tail, per graph ------
// (unchanged from R7: Adj LDS-staged once; phase-ahead weight prefetch)
struct GTParams {
  const void* X;
  const float* Adj;
  const short* W1t; const float* b1;
  const short* W2t; const float* b2;
  float* p1; float* p2;
  const short* Wv0t;   // [256][264]
  const short* Ubart;  // [100][264] (pre-scaled 1/16)
  const float* biasVS; // [bv0(256) | cvec(100)]
  const float* Q0;
  const short* Wo0t;  const float* bo0;
  const short* WQKVt; const float* biasQKV;
  const short* Wo1t;  const float* bo1;
  const float *S2w, *Wq2, *bq2, *Wv2, *bv2, *Wo2, *bo2, *Wl, *bl, *Wc1, *bc1, *Wc2, *bc2, *Wc3, *bc3;
  float* out;
};

__global__ __launch_bounds__(512) void gcn_tail(GTParams P)
{
  __shared__ __align__(16) char pool[162880];
  __shared__ float dinvL[112];
  __shared__ int flagS;
  // gcn aliases
  short* S1x = (short*)(pool);            // X-stage, then x1 A-layout
  short* S2b = (short*)(pool + 30464);
  short* S4b = (short*)(pool + 65280);
  short* Asb = (short*)(pool + 100096);
  float* AdjL = (float*)(pool + 30464);   // raw counts [100][100] f32; dead before p1 writes S2b
  // tail region bases
  char* R1 = pool;
  char* RV = pool + 57344;
  char* RS = pool + 122880;
  float* Ssh  = (float*)RS;            // [100][100]
  short* Pbf  = (short*)R1;            // [4][32][136]
  short* Abf  = (short*)(R1 + 34816);  // [32][264]
  float* hva  = (float*)(R1 + 51712);
  float* hvb  = (float*)(R1 + 52224);
  float* O1F  = (float*)R1;            // [25][132]
  float* OaF  = (float*)RS;            // [25][260]
  float* ObF  = (float*)RS;            // [25][132]
  short* Abf2 = (short*)(RS + 26000);  // [32][136]
  float* QKV  = (float*)RV;            // [25][388]
  float* Ss2  = (float*)(RV + 38800);  // [4][25][26]
  float* hpart= (float*)(RV + 38800);

  int g = blockIdx.x, tid = threadIdx.x;
  bool isbf = block_sniff(P.X, tid, &flagS);
  int wave = tid >> 6, lane = tid & 63, quad = lane >> 4, l16 = lane & 15;
  int gn = wave * 16 + l16;

  // prefetch W1/W2 B-frags at t=0 (consumed p1 / p4)
  s16x8 w1f[4], w2f[4];
#pragma unroll
  for (int kt = 0; kt < 4; kt++){
    int kb = kt * 32 + quad * 8;
    w1f[kt] = *reinterpret_cast<const s16x8*>(P.W1t + (size_t)gn * 136 + kb);
    w2f[kt] = *reinterpret_cast<const s16x8*>(P.W2t + (size_t)gn * 136 + kb);
  }

  // P0: zero whole pool once (all stale-LDS hazards die here)
  for (int i = tid; i < 162880 / 4; i += 512) ((int*)pool)[i] = 0;
  __syncthreads();

  // P1: coalesced stage of raw Adj counts + X
  {
    const float* Ag = P.Adj + (size_t)g * (MAXN * MAXN);
    for (int i = tid; i < 2500; i += 512)
      ((float4*)AdjL)[i] = ((const float4*)Ag)[i];
  }
  for (int i = tid; i < MAXN * 16; i += 512){
    int r = i >> 4, k8 = (i & 15) << 3;
    s16x8 v;
    if (isbf){
      v = *reinterpret_cast<const s16x8*>((const short*)P.X + (size_t)(g * MAXN + r) * 128 + k8);
    } else {
      const float* ap = (const float*)P.X + (size_t)(g * MAXN + r) * 128 + k8;
      float4 f0 = *reinterpret_cast<const float4*>(ap);
      float4 f1 = *reinterpret_cast<const float4*>(ap + 4);
      v[0] = f2bf(f0.x); v[1] = f2bf(f0.y); v[2] = f2bf(f0.z); v[3] = f2bf(f0.w);
      v[4] = f2bf(f1.x); v[5] = f2bf(f1.y); v[6] = f2bf(f1.z); v[7] = f2bf(f1.w);
    }
    *reinterpret_cast<s16x8*>(&S1x[r * GLDK + k8]) = v;
  }
  __syncthreads();

  // P2: deg[r] = 1 + rowsum (from LDS); 4 lanes/row + shfl reduce
  if (tid < 400){
    int r = tid >> 2, j0 = (tid & 3) * 25;
    const float* row = AdjL + r * 100 + j0;
    float s = 0.f;
#pragma unroll
    for (int j = 0; j < 25; j++) s += row[j];
    s += __shfl_xor(s, 1); s += __shfl_xor(s, 2);
    if ((tid & 3) == 0) dinvL[r] = rsqrtf(1.0f + s);
  }
  __syncthreads();

  // P3: normalize (LDS->LDS): Asb = (cnt + I) * dinv[r]*dinv[s]
  for (int i = tid; i < MAXN * MAXN; i += 512){
    int r = i / MAXN, s = i - r * MAXN;
    float v = AdjL[i] + (r == s ? 1.0f : 0.0f);
    Asb[r * GLDK + s] = f2bf(v * dinvL[r] * dinvL[s]);
  }
  __syncthreads();

  f32x4 acc[7];
  auto zacc = [&](){
#pragma unroll
    for (int rt = 0; rt < 7; rt++) acc[rt] = (f32x4){0.f,0.f,0.f,0.f};
  };
  auto passL = [&](const short* Abuf, const short* Bbuf){
#pragma unroll
    for (int kt = 0; kt < 4; kt++){
      int kb = kt * 32 + quad * 8;
      s16x8 bf0 = *reinterpret_cast<const s16x8*>(&Bbuf[gn * GLDK + kb]);
#pragma unroll
      for (int rt = 0; rt < 7; rt++){
        s16x8 a = *reinterpret_cast<const s16x8*>(&Abuf[(rt * 16 + l16) * GLDK + kb]);
        acc[rt] = __builtin_amdgcn_mfma_f32_16x16x32_bf16(a, bf0, acc[rt], 0, 0, 0);
      }
    }
  };
  auto passGF = [&](const short* Abuf, const s16x8* bfr){
#pragma unroll
    for (int kt = 0; kt < 4; kt++){
      int kb = kt * 32 + quad * 8;
#pragma unroll
      for (int rt = 0; rt < 7; rt++){
        s16x8 a = *reinterpret_cast<const s16x8*>(&Abuf[(rt * 16 + l16) * GLDK + kb]);
        acc[rt] = __builtin_amdgcn_mfma_f32_16x16x32_bf16(a, bfr[kt], acc[rt], 0, 0, 0);
      }
    }
  };
  auto writeB = [&](short* Bbuf){
#pragma unroll
    for (int rt = 0; rt < 7; rt++){
      short4 o;
      o.x = f2bf(acc[rt][0]); o.y = f2bf(acc[rt][1]);
      o.z = f2bf(acc[rt][2]); o.w = f2bf(acc[rt][3]);
      *reinterpret_cast<short4*>(&Bbuf[gn * GLDK + rt * 16 + quad * 4]) = o;
    }
  };
  float s1sum = 0.f, s2sum = 0.f;
  auto hopEpi = [&](const float* bias, short* AoutA, short* BoutB, float& sum){
    float bv = bias[gn];
#pragma unroll
    for (int rt = 0; rt < 7; rt++){
      float vals[4];
#pragma unroll
      for (int r = 0; r < 4; r++){
        int row = rt * 16 + quad * 4 + r;
        float v = fmaxf(acc[rt][r] + bv, 0.f);
        vals[r] = v;
        if (row < MAXN) sum += v;
      }
      short4 o;
      o.x = f2bf(vals[0]); o.y = f2bf(vals[1]); o.z = f2bf(vals[2]); o.w = f2bf(vals[3]);
      *reinterpret_cast<short4*>(&BoutB[gn * GLDK + rt * 16 + quad * 4]) = o;
      if (AoutA){
        AoutA[(rt * 16 + quad * 4 + 0) * GLDK + gn] = o.x;
        AoutA[(rt * 16 + quad * 4 + 1) * GLDK + gn] = o.y;
        AoutA[(rt * 16 + quad * 4 + 2) * GLDK + gn] = o.z;
        AoutA[(rt * 16 + quad * 4 + 3) * GLDK + gn] = o.w;
      }
    }
  };

  // p1: S2 = X@W1
  zacc(); passGF(S1x, w1f); writeB(S2b);
  __syncthreads();
  // p2: x1 = relu(A·S2 + b1) -> S4 (B^T) + S1x (A-layout)
  zacc(); passL(Asb, S2b); hopEpi(P.b1, S1x, S4b, s1sum);
  __syncthreads();
  // p3: xagg cols 0..127 = A·x1 -> stash in regs
  short4 xag0[7];
  zacc(); passL(Asb, S4b);
#pragma unroll
  for (int rt = 0; rt < 7; rt++){
    xag0[rt].x = f2bf(acc[rt][0]); xag0[rt].y = f2bf(acc[rt][1]);
    xag0[rt].z = f2bf(acc[rt][2]); xag0[rt].w = f2bf(acc[rt][3]);
  }
  // p4: S2 = x1@W2 (no barrier: reads S1x, writes S2b; prior S2b reads done pre-p3-barrier)
  zacc(); passGF(S1x, w2f); writeB(S2b);
  __syncthreads();
  // p5: x2 = relu(A·S2 + b2) -> S4
  zacc(); passL(Asb, S2b); hopEpi(P.b2, nullptr, S4b, s2sum);
  __syncthreads();
  // p6: xagg cols 128..255 = A·x2 (stays in acc)
  zacc(); passL(Asb, S4b);

  // prefetch T1 weights (Wv0/Ubar) before the xagg-write barrier
  s16x8 wvf[2][8], ubf[8];
  {
#pragma unroll
    for (int cg = 0; cg < 2; cg++){
      int c = wave * 32 + cg * 16 + l16;
      const short* bw = P.Wv0t + (size_t)c * 264;
#pragma unroll
      for (int kt = 0; kt < 8; kt++) wvf[cg][kt] = *reinterpret_cast<const s16x8*>(bw + kt * 32 + quad * 8);
    }
    int jj = (wave < 7) ? (wave * 16 + l16) : l16;
    const short* bw = P.Ubart + (size_t)jj * 264;
#pragma unroll
    for (int kt = 0; kt < 8; kt++) ubf[kt] = *reinterpret_cast<const s16x8*>(bw + kt * 32 + quad * 8);
  }

  s1sum += __shfl_xor(s1sum, 16); s1sum += __shfl_xor(s1sum, 32);
  s2sum += __shfl_xor(s2sum, 16); s2sum += __shfl_xor(s2sum, 32);
  if (quad == 0){
    P.p1[g * 128 + gn] = s1sum;
    P.p2[g * 128 + gn] = s2sum;
  }
  __syncthreads();   // all p6 reads of Asb/S4b done before pool reuse

  // write xagg (both halves) into R1 swizzled; zero rows 100..111
  {
    short v0[4];
#pragma unroll
    for (int rt = 0; rt < 7; rt++){
      v0[0] = xag0[rt].x; v0[1] = xag0[rt].y; v0[2] = xag0[rt].z; v0[3] = xag0[rt].w;
#pragma unroll
      for (int r = 0; r < 4; r++){
        int node = rt * 16 + quad * 4 + r;
        if (node < MAXN){
          int sw = (node & 7) << 4;
          *(short*)(R1 + ((node * 512 + gn * 2) ^ sw)) = v0[r];
          *(short*)(R1 + ((node * 512 + (gn + 128) * 2) ^ sw)) = f2bf(acc[rt][r]);
        }
      }
    }
    for (int i = tid; i < 1536; i += 512) ((int*)(R1 + 51200))[i] = 0;
  }
  __syncthreads();

  // ---- T1: fused GEMMs on xagg: V = xagg@Wv0 -> VT (swz), S = xagg@Ubar^T -> Ssh ----
  {
#pragma unroll
    for (int cg = 0; cg < 2; cg++){
      int c = wave * 32 + cg * 16 + l16;
      f32x4 vac[7];
#pragma unroll
      for (int rt = 0; rt < 7; rt++) vac[rt] = (f32x4){0.f,0.f,0.f,0.f};
#pragma unroll
      for (int kt = 0; kt < 8; kt++){
        int kb = kt * 32 + quad * 8;
#pragma unroll
        for (int rt = 0; rt < 7; rt++){
          int row = rt * 16 + l16;
          int ab = (row * 512 + kb * 2) ^ ((row & 7) << 4);
          s16x8 a = *reinterpret_cast<const s16x8*>(R1 + ab);
          vac[rt] = __builtin_amdgcn_mfma_f32_16x16x32_bf16(a, wvf[cg][kt], vac[rt], 0, 0, 0);
        }
      }
      float bv = P.biasVS[c];
#pragma unroll
      for (int rt = 0; rt < 7; rt++){
        int node0 = rt * 16 + quad * 4;
        short4 o;
        o.x = f2bf(vac[rt][0] + bv); o.y = f2bf(vac[rt][1] + bv);
        o.z = f2bf(vac[rt][2] + bv); o.w = f2bf(vac[rt][3] + bv);
        int b = (c * 256 + node0 * 2) ^ ((c & 7) << 4);
        *reinterpret_cast<short4*>(RV + b) = o;
      }
    }
    if (wave < 7){
      int j = wave * 16 + l16;
      f32x4 sac[7];
#pragma unroll
      for (int rt = 0; rt < 7; rt++) sac[rt] = (f32x4){0.f,0.f,0.f,0.f};
#pragma unroll
      for (int kt = 0; kt < 8; kt++){
        int kb = kt * 32 + quad * 8;
#pragma unroll
        for (int rt = 0; rt < 7; rt++){
          int row = rt * 16 + l16;
          int ab = (row * 512 + kb * 2) ^ ((row & 7) << 4);
          s16x8 a = *reinterpret_cast<const s16x8*>(R1 + ab);
          sac[rt] = __builtin_amdgcn_mfma_f32_16x16x32_bf16(a, ubf[kt], sac[rt], 0, 0, 0);
        }
      }
      if (j < 100){
        float cv = P.biasVS[256 + j];
#pragma unroll
        for (int rt = 0; rt < 7; rt++){
#pragma unroll
          for (int r = 0; r < 4; r++){
            int node = rt * 16 + quad * 4 + r;
            if (node < MAXN) Ssh[node * 100 + j] = sac[rt][r] + cv;
          }
        }
      }
    }
  }
  __syncthreads();

  // ---- T2: fused softmax+transpose -> Pbf; spare threads zero Pbf k in [100,128) ----
  if (tid < 400){
    int k = tid >> 2, h = tid & 3;
    const float* base = &Ssh[k * 100 + h * 25];
    float v[25];
    float m = -1e30f;
#pragma unroll
    for (int q = 0; q < 25; q++){ v[q] = base[q]; m = fmaxf(m, v[q]); }
    float s = 0.f;
#pragma unroll
    for (int q = 0; q < 25; q++){ float e = __expf(v[q] - m); v[q] = e; s += e; }
    float inv = 1.0f / s;
    short* pb = &Pbf[h * 32 * 136 + k];
#pragma unroll
    for (int q = 0; q < 25; q++) pb[q * 136] = f2bf(v[q] * inv);
  } else {
    for (int idx = tid - 400; idx < 1400; idx += 112){
      int r = idx / 14, c = idx - r * 14;
      int h = r / 25, q = r - h * 25;
      ((int*)Pbf)[(h * 32 + q) * 68 + 50 + c] = 0;
    }
  }
  __syncthreads();

  // ---- T3: AV via MFMA; B-frags from swizzled VT ----
  {
    int h = wave >> 1;
    int cbase = wave * 32;
    f32x4 aac[2][2];
#pragma unroll
    for (int rt = 0; rt < 2; rt++){ aac[rt][0] = (f32x4){0.f,0.f,0.f,0.f}; aac[rt][1] = aac[rt][0]; }
#pragma unroll
    for (int kt = 0; kt < 4; kt++){
      int kb = kt * 32 + quad * 8;
      int c0 = cbase + l16, c1 = cbase + 16 + l16;
      int b0 = (c0 * 256 + kb * 2) ^ ((c0 & 7) << 4);
      int b1 = (c1 * 256 + kb * 2) ^ ((c1 & 7) << 4);
      s16x8 vb0 = *reinterpret_cast<const s16x8*>(RV + b0);
      s16x8 vb1 = *reinterpret_cast<const s16x8*>(RV + b1);
#pragma unroll
      for (int rt = 0; rt < 2; rt++){
        s16x8 a = *reinterpret_cast<const s16x8*>(&Pbf[(h * 32 + rt * 16 + l16) * 136 + kb]);
        aac[rt][0] = __builtin_amdgcn_mfma_f32_16x16x32_bf16(a, vb0, aac[rt][0], 0, 0, 0);
        aac[rt][1] = __builtin_amdgcn_mfma_f32_16x16x32_bf16(a, vb1, aac[rt][1], 0, 0, 0);
      }
    }
    // prefetch Wo0 B-frags before the barrier (consumed next phase)
    s16x8 o0f0[8], o0f1[8];
    {
      int c0w = wave * 16 + l16, c1w = c0w + 128;
#pragma unroll
      for (int kt = 0; kt < 8; kt++){
        int kb = kt * 32 + quad * 8;
        o0f0[kt] = *reinterpret_cast<const s16x8*>(&P.Wo0t[(size_t)c0w * 264 + kb]);
        o0f1[kt] = *reinterpret_cast<const s16x8*>(&P.Wo0t[(size_t)c1w * 264 + kb]);
      }
    }
#pragma unroll
    for (int cg = 0; cg < 2; cg++){
      int c = cbase + cg * 16 + l16;
#pragma unroll
      for (int rt = 0; rt < 2; rt++){
#pragma unroll
        for (int r = 0; r < 4; r++){
          int row = rt * 16 + quad * 4 + r;
          if (row < 25){
            float oa = aac[rt][cg][r] + P.Q0[row * 256 + c];
            OaF[row * 260 + c] = oa;
            Abf[row * 264 + c] = f2bf(oa);
          }
        }
      }
    }
    __syncthreads();

    // Wo0 (B-frags prefetched)
    {
      int c0 = wave * 16 + l16, c1 = c0 + 128;
      f32x4 a0[2], a1[2];
#pragma unroll
      for (int rt = 0; rt < 2; rt++){ a0[rt] = (f32x4){0.f,0.f,0.f,0.f}; a1[rt] = a0[rt]; }
#pragma unroll
      for (int kt = 0; kt < 8; kt++){
        int kb = kt * 32 + quad * 8;
#pragma unroll
        for (int rt = 0; rt < 2; rt++){
          s16x8 a = *reinterpret_cast<const s16x8*>(&Abf[(rt * 16 + l16) * 264 + kb]);
          a0[rt] = __builtin_amdgcn_mfma_f32_16x16x32_bf16(a, o0f0[kt], a0[rt], 0, 0, 0);
          a1[rt] = __builtin_amdgcn_mfma_f32_16x16x32_bf16(a, o0f1[kt], a1[rt], 0, 0, 0);
        }
      }
      __syncthreads();
#pragma unroll
      for (int cg = 0; cg < 2; cg++){
        int col = cg ? c1 : c0;
        float bv = P.bo0[col];
#pragma unroll
        for (int rt = 0; rt < 2; rt++){
          f32x4 av = cg ? a1[rt] : a0[rt];
#pragma unroll
          for (int r = 0; r < 4; r++){
            int row = rt * 16 + quad * 4 + r;
            if (row < 25){
              float t = av[r] + bv;
              Abf[row * 264 + col] = f2bf(OaF[row * 260 + col] + fmaxf(t, 0.f));
            }
          }
        }
      }
    }
  }
  // prefetch QKV B-frags before the barrier (consumed next phase)
  s16x8 qkvf[3][8];
  {
    int c0 = wave * 16 + l16;
#pragma unroll
    for (int p2 = 0; p2 < 3; p2++)
#pragma unroll
      for (int kt = 0; kt < 8; kt++){
        int kb = kt * 32 + quad * 8;
        qkvf[p2][kt] = *reinterpret_cast<const s16x8*>(&P.WQKVt[(size_t)(c0 + p2 * 128) * 264 + kb]);
      }
  }
  __syncthreads();

  // QKV (B-frags prefetched)
  {
    int c0 = wave * 16 + l16;
    f32x4 qac[3][2];
#pragma unroll
    for (int p2 = 0; p2 < 3; p2++)
#pragma unroll
      for (int rt = 0; rt < 2; rt++) qac[p2][rt] = (f32x4){0.f,0.f,0.f,0.f};
#pragma unroll
    for (int kt = 0; kt < 8; kt++){
      int kb = kt * 32 + quad * 8;
#pragma unroll
      for (int rt = 0; rt < 2; rt++){
        s16x8 a = *reinterpret_cast<const s16x8*>(&Abf[(rt * 16 + l16) * 264 + kb]);
#pragma unroll
        for (int p2 = 0; p2 < 3; p2++)
          qac[p2][rt] = __builtin_amdgcn_mfma_f32_16x16x32_bf16(a, qkvf[p2][kt], qac[p2][rt], 0, 0, 0);
      }
    }
#pragma unroll
    for (int p2 = 0; p2 < 3; p2++){
      int col = c0 + p2 * 128;
      float bv = P.biasQKV[col];
#pragma unroll
      for (int rt = 0; rt < 2; rt++){
#pragma unroll
        for (int r = 0; r < 4; r++){
          int row = rt * 16 + quad * 4 + r;
          if (row < 25) QKV[row * 388 + col] = qac[p2][rt][r] + bv;
        }
      }
    }
  }
  __syncthreads();

  // SAB scores
  for (int idx = tid; idx < 2500; idx += 512){
    int h = idx / 625;
    int r = idx - h * 625;
    int q = r / 25, k = r - q * 25;
    const float* qp = &QKV[q * 388 + h * 32];
    const float* kp = &QKV[k * 388 + 128 + h * 32];
    float sac = 0.f;
#pragma unroll
    for (int d = 0; d < 32; d += 4){
      float4 a4 = *reinterpret_cast<const float4*>(&qp[d]);
      float4 b4 = *reinterpret_cast<const float4*>(&kp[d]);
      sac = fmaf(a4.x, b4.x, sac); sac = fmaf(a4.y, b4.y, sac);
      sac = fmaf(a4.z, b4.z, sac); sac = fmaf(a4.w, b4.w, sac);
    }
    Ss2[(h * 25 + q) * 26 + k] = sac * 0.0883883476f;
  }
  __syncthreads();
  if (tid < 100){
    int h = tid / 25, k = tid - h * 25;
    float m = -1e30f;
#pragma unroll
    for (int q = 0; q < 25; q++) m = fmaxf(m, Ss2[(h * 25 + q) * 26 + k]);
    float s = 0.f;
#pragma unroll
    for (int q = 0; q < 25; q++){ float e = __expf(Ss2[(h * 25 + q) * 26 + k] - m); Ss2[(h * 25 + q) * 26 + k] = e; s += e; }
    float inv = 1.0f / s;
#pragma unroll
    for (int q = 0; q < 25; q++) Ss2[(h * 25 + q) * 26 + k] *= inv;
  }
  __syncthreads();

  // Ob = Q1 + AV, q-split across tid<256
  if (tid < 256){
    int qh = tid >> 7;
    int c = tid & 127, h = c >> 5;
    int q0 = qh * 13, nq = 13 - qh;
    float oac[13] = {};
    for (int k = 0; k < 25; k++){
      float v = QKV[k * 388 + 256 + c];
      for (int j = 0; j < nq; j++)
        oac[j] = fmaf(Ss2[(h * 25 + q0 + j) * 26 + k], v, oac[j]);
    }
    for (int j = 0; j < nq; j++){
      int q = q0 + j;
      float ob = QKV[q * 388 + c] + oac[j];
      ObF[q * 132 + c] = ob;
      Abf2[q * 136 + c] = f2bf(ob);
    }
  }
  // prefetch Wo1 B-frags before the barrier (consumed next phase; all 512 threads)
  s16x8 o1f[4];
  {
    int c0 = wave * 16 + l16;
#pragma unroll
    for (int kt = 0; kt < 4; kt++){
      int kb = kt * 32 + quad * 8;
      o1f[kt] = *reinterpret_cast<const s16x8*>(&P.Wo1t[(size_t)c0 * 136 + kb]);
    }
  }
  __syncthreads();

  // O1 = Ob + relu(Ob @ Wo1 + bo1)
  {
    int c0 = wave * 16 + l16;
    f32x4 a0 = (f32x4){0.f,0.f,0.f,0.f}, a1 = a0;
#pragma unroll
    for (int kt = 0; kt < 4; kt++){
      int kb = kt * 32 + quad * 8;
      s16x8 aA = *reinterpret_cast<const s16x8*>(&Abf2[l16 * 136 + kb]);
      s16x8 aB = *reinterpret_cast<const s16x8*>(&Abf2[(16 + l16) * 136 + kb]);
      a0 = __builtin_amdgcn_mfma_f32_16x16x32_bf16(aA, o1f[kt], a0, 0, 0, 0);
      a1 = __builtin_amdgcn_mfma_f32_16x16x32_bf16(aB, o1f[kt], a1, 0, 0, 0);
    }
    float bv = P.bo1[c0];
#pragma unroll
    for (int r = 0; r < 4; r++){
      int row0 = quad * 4 + r;
      if (row0 < 25){ float t = a0[r] + bv; O1F[row0 * 132 + c0] = ObF[row0 * 132 + c0] + fmaxf(t, 0.f); }
      int row1 = 16 + quad * 4 + r;
      if (row1 < 25){ float t = a1[r] + bv; O1F[row1 * 132 + c0] = ObF[row1 * 132 + c0] + fmaxf(t, 0.f); }
    }
  }
  __syncthreads();

  // head: colsum then 4-way k-split matvec chain
  if (tid < 128){
    float s = 0.f;
    for (int k = 0; k < 25; k++) s += O1F[k * 132 + tid];
    hva[tid] = s;
  }
  __syncthreads();
  {
    int kh = tid >> 7, c = tid & 127, k0 = kh * 32;
    float s = 0.f;
    for (int k = k0; k < k0 + 32; k++)
      s = fmaf(P.S2w[k], P.Wq2[k * 128 + c], fmaf(hva[k], P.Wv2[k * 128 + c], s));
    hpart[kh * 128 + c] = s;
    __syncthreads();
    if (tid < 128) hvb[c] = hpart[c] + hpart[128 + c] + hpart[256 + c] + hpart[384 + c]
                          + P.bq2[c] + 25.f * P.bv2[c];
    __syncthreads();
    s = 0.f;
    for (int k = k0; k < k0 + 32; k++) s = fmaf(hvb[k], P.Wo2[k * 128 + c], s);
    hpart[kh * 128 + c] = s;
    __syncthreads();
    if (tid < 128) hva[c] = hvb[c] + fmaxf(hpart[c] + hpart[128 + c] + hpart[256 + c] + hpart[384 + c] + P.bo2[c], 0.f);
    __syncthreads();
    s = 0.f;
    for (int k = k0; k < k0 + 32; k++) s = fmaf(hva[k], P.Wl[k * 128 + c], s);
    hpart[kh * 128 + c] = s;
    __syncthreads();
    if (tid < 128) hvb[c] = hpart[c] + hpart[128 + c] + hpart[256 + c] + hpart[384 + c] + P.bl[c];
    __syncthreads();
    s = 0.f;
    for (int k = k0; k < k0 + 32; k++) s = fmaf(hvb[k], P.Wc1[k * 128 + c], s);
    hpart[kh * 128 + c] = s;
    __syncthreads();
    if (tid < 128) hva[c] = fmaxf(hpart[c] + hpart[128 + c] + hpart[256 + c] + hpart[384 + c] + P.bc1[c], 0.f);
    __syncthreads();
    {
      int kh2 = tid >> 6, c2 = tid & 63, kk0 = kh2 * 16;
      float s2 = 0.f;
      for (int k = kk0; k < kk0 + 16; k++) s2 = fmaf(hva[k], P.Wc2[k * 64 + c2], s2);
      hpart[kh2 * 64 + c2] = s2;
    }
    __syncthreads();
    if (tid < 64){
      float s2 = hpart[tid] + hpart[64 + tid] + hpart[128 + tid] + hpart[192 + tid]
               + hpart[256 + tid] + hpart[320 + tid] + hpart[384 + tid] + hpart[448 + tid];
      hvb[tid] = fmaxf(s2 + P.bc2[tid], 0.f);
    }
    __syncthreads();
    if (tid < 10){
      float lg = P.bc3[tid];
      for (int k = 0; k < 64; k++) lg = fmaf(hvb[k], P.Wc3[k * 10 + tid], lg);
      P.out[g * 10 + tid] = lg;
    }
  }
}

// ---------------- host ----------------
extern "C" void kernel_launch(void* const* d_in, const int* in_sizes, int n_in,
                              void* d_out, int out_size, void* d_ws, size_t ws_size,
                              hipStream_t stream)
{
  const int*  edge = (const int*)d_in[1];
  const int N = in_sizes[0] / FIN;      // 20000
  const int E = in_sizes[1] / 2;        // 320000
  const int G = N / MAXN;               // 200
  const int* srcp = edge;
  const int* dstp = edge + E;
  float* out = (float*)d_out;           // f32: [logits 200x10 | p1 200x128 | p2 200x128]

  float* w = (float*)d_ws;
  size_t off = 0;
  auto alloc = [&](size_t nfl){ nfl = (nfl + 3) & ~(size_t)3; float* p = w + off; off += nfl; return p; };
  auto allocS = [&](size_t nsh)->short*{ size_t nfl = ((nsh + 1) / 2 + 3) & ~(size_t)3; short* p = (short*)(w + off); off += nfl; return p; };

  float* biasVS  = alloc(356);          // [bv0 | cvec]
  float* biasQKV = alloc(384);          // [bq1 | bk1 | bv1]
  float* cvec = biasVS + 256;

  const int castT[24] = {4,6,7,8,9,10,11,15,23,24,25,26,29,30,31,32,33,34,35,36,37,38,39,40};
  float* wf[41] = {nullptr};
  for (int i = 0; i < 24; i++) wf[castT[i]] = alloc((size_t)in_sizes[castT[i]]);
  wf[13] = biasVS; wf[17] = biasQKV; wf[19] = biasQKV + 128; wf[21] = biasQKV + 256;

  float* Adj = alloc((size_t)G * MAXN * MAXN);     // unnormalized counts
  float* Q0  = alloc(25 * 256);

  short* W1t   = allocS(128 * 136);
  short* W2t   = allocS(128 * 136);
  short* WVSt  = allocS(356 * 264);     // [Wv0t | Ubart]
  short* WQKVt = allocS(384 * 264);     // [Wq1t | Wk1t | Wv1t]
  short* Wo0t  = allocS(256 * 264);
  short* Wo1t  = allocS(128 * 136);
  short* Ubart = WVSt + (size_t)256 * 264;
  if (off * sizeof(float) > ws_size) return;

  dim3 blk(256);

  // 1. unified prep (inline sniff; casts + TILED transposes + Adj=0 fill)
  PrepBatch pb; int ne = 0, blks = 0;
  pb.xptr = d_in[0];
  auto addC = [&](const void* s, float* d, int n){
    pb.src[ne]=s; pb.dst[ne]=d; pb.a[ne]=n; pb.b[ne]=0; pb.blk0[ne]=blks;
    blks += ceil_div(ceil_div(n, 4), 256); ne++; };
  auto addW = [&](const void* s, short* d, int K, int Nn){
    pb.src[ne]=s; pb.dst[ne]=d; pb.a[ne]=K; pb.b[ne]=Nn; pb.blk0[ne]=blks;
    blks += (K >> 6) * (Nn >> 6); ne++; };
  auto addF = [&](void* d, int n, int mode){
    pb.src[ne]=nullptr; pb.dst[ne]=d; pb.a[ne]=n; pb.b[ne]=mode; pb.blk0[ne]=blks;
    blks += ceil_div(ceil_div(n, 4), 256); ne++; };
  for (int i = 0; i < 24; i++){ int t = castT[i]; addC(d_in[t], wf[t], in_sizes[t]); }
  addC(d_in[13], biasVS, 256);
  addC(d_in[17], biasQKV, 128); addC(d_in[19], biasQKV + 128, 128); addC(d_in[21], biasQKV + 256, 128);
  addW(d_in[3],  W1t, 128, 128);             addW(d_in[5],  W2t, 128, 128);
  addW(d_in[12], WVSt, 256, 256);            addW(d_in[16], WQKVt, 256, 128);
  addW(d_in[18], WQKVt + 128*264, 256, 128); addW(d_in[20], WQKVt + 256*264, 256, 128);
  addW(d_in[14], Wo0t, 256, 256);            addW(d_in[22], Wo1t, 128, 128);
  addF(Adj, G * MAXN * MAXN, -1);
  pb.blk0[ne] = blks; pb.ne = ne;
  prep_all<<<dim3(blks), blk, 0, stream>>>(pb);

  // 2. edge counts
  adj_cnt<<<ceil_div(E, 256), blk, 0, stream>>>(srcp, dstp, Adj, E);

  // 3. Q0 + Ubar^T + cvec (k-split version)
  ubar_q0<<<dim3(100), blk, 0, stream>>>(wf[7], wf[8], wf[9], wf[10], wf[11], Q0, Ubart, cvec);

  // 4. fused GCN + tail megakernel (unchanged from R7)
  GTParams tp;
  tp.X = d_in[0]; tp.Adj = Adj;
  tp.W1t = W1t; tp.b1 = wf[4]; tp.W2t = W2t; tp.b2 = wf[6];
  tp.p1 = out + 2000; tp.p2 = out + 27600;
  tp.Wv0t = WVSt; tp.Ubart = Ubart; tp.biasVS = biasVS;
  tp.Q0 = Q0;
  tp.Wo0t = Wo0t; tp.bo0 = wf[15];
  tp.WQKVt = WQKVt; tp.biasQKV = biasQKV;
  tp.Wo1t = Wo1t; tp.bo1 = wf[23];
  tp.S2w = wf[24]; tp.Wq2 = wf[25]; tp.bq2 = wf[26]; tp.Wv2 = wf[29]; tp.bv2 = wf[30];
  tp.Wo2 = wf[31]; tp.bo2 = wf[32]; tp.Wl = wf[33]; tp.bl = wf[34];
  tp.Wc1 = wf[35]; tp.bc1 = wf[36]; tp.Wc2 = wf[37]; tp.bc2 = wf[38];
  tp.Wc3 = wf[39]; tp.bc3 = wf[40];
  tp.out = out;
  gcn_tail<<<dim3(G), dim3(512), 0, stream>>>(tp);
}

// Round 9
// 224.198 us; speedup vs baseline: 1.0387x; 1.0387x over previous
//
#include <hip/hip_runtime.h>
#include <hip/hip_bf16.h>
#include <cstdint>
#include <cstddef>

typedef __hip_bfloat16 bf16;
typedef __attribute__((ext_vector_type(8))) short s16x8;
typedef __attribute__((ext_vector_type(4))) float f32x4;

#define MAXN 100
#define HH   4
#define FIN  128
#define KS1  25
#define GLDK 136

static inline int ceil_div(int a, int b){ return (a + b - 1) / b; }

__device__ inline short f2bf(float f){               // RNE float->bf16 bits
  unsigned int u = __float_as_uint(f);
  u = (u + 0x7FFF + ((u >> 16) & 1)) >> 16;
  return (short)u;
}
__device__ inline float loadf(const void* s, size_t i, bool isbf){
  return isbf ? __bfloat162float(((const bf16*)s)[i]) : ((const float*)s)[i];
}
// LDS-only barrier: drain LDS ops, sync threads, leave global loads in flight.
// (__syncthreads lowers to s_waitcnt vmcnt(0) lgkmcnt(0); s_barrier — the vmcnt(0)
//  drain serializes prefetched weight loads at every phase boundary. All inter-phase
//  data in gcn_tail flows through LDS via same-thread reg->ds_write, so lgkmcnt(0)
//  + s_barrier is sufficient; register-destined global loads get auto vmcnt waits
//  at first use.)
__device__ inline void barrier_lds(){
  asm volatile("s_waitcnt lgkmcnt(0)" ::: "memory");
  __builtin_amdgcn_s_barrier();
}
// per-block dtype sniff: wave-0 lanes sample x's even half-words; bf16 data decodes
// sane ~100%, f32 low-halves ~11% -> popcount threshold 32 of 64.
__device__ inline bool block_sniff(const void* x, int tid, int* flagS){
  if (tid < 64){
    unsigned short b = ((const unsigned short*)x)[2 * tid];
    float v = __uint_as_float(((unsigned)b) << 16);
    float a = fabsf(v);
    bool ok = (a >= 6.1e-5f && a <= 16384.f);
    unsigned long long m = __ballot(ok);
    if (tid == 0) *flagS = (__popcll(m) >= 32) ? 1 : 0;
  }
  __syncthreads();
  return *flagS != 0;
}

// ---------------- unified prep: casts + TILED transposes + edge atomics, flat 1-D grid --------
// Edge blocks appended after task blocks (Adj pre-zeroed by hipMemsetAsync).
struct PrepBatch {
  const void* src[40];
  void*       dst[40];
  int         a[40];
  int         b[40];     // 0: cast, >0: wprep N
  int         blk0[41];
  int         ne;
  int         nTaskBlks;
  const void* xptr;      // for inline sniff
  const int *esrc, *edst; float* eadj; int ecnt;
};

__global__ __launch_bounds__(256) void prep_all(PrepBatch pb){
  __shared__ int flagS;
  __shared__ short T[64][66];
  int tid = threadIdx.x;
  int blk = blockIdx.x;

  if (blk >= pb.nTaskBlks){
    // ---- edge count block: cnt[g][dl][sl] += 1 (exact in fp32) ----
    int i = (blk - pb.nTaskBlks) * 256 + tid;
    if (i < pb.ecnt){
      int s = pb.esrc[i], d = pb.edst[i];
      int g = d / MAXN;
      int dl = d - g * MAXN;
      int sl = s - (s / MAXN) * MAXN;
      atomicAdd(&pb.eadj[(size_t)g * (MAXN * MAXN) + dl * MAXN + sl], 1.0f);
    }
    return;
  }

  bool isbf = block_sniff(pb.xptr, tid, &flagS);
  int t = 0;
  while (t + 1 < pb.ne && pb.blk0[t + 1] <= blk) t++;
  int local = blk - pb.blk0[t];
  const void* s = pb.src[t];
  int bt = pb.b[t];
  if (bt == 0){
    int n = pb.a[t];
    float* d = (float*)pb.dst[t];
    int v = local * 256 + tid;
    int base = v * 4;
    if (base + 3 < n){
      float4 f;
      if (isbf){
        ushort4 u = ((const ushort4*)s)[v];
        f.x = __uint_as_float(((unsigned)u.x) << 16);
        f.y = __uint_as_float(((unsigned)u.y) << 16);
        f.z = __uint_as_float(((unsigned)u.z) << 16);
        f.w = __uint_as_float(((unsigned)u.w) << 16);
      } else f = ((const float4*)s)[v];
      ((float4*)d)[v] = f;
    } else {
      for (int j = base; j < n && j < base + 4; j++) d[j] = loadf(s, j, isbf);
    }
  } else {
    // tiled transpose: source W[K][Nn] row-major -> dest WT[Nn][ldt=K+8] bf16
    int K = pb.a[t], Nn = bt, ldt = K + 8;
    short* d = (short*)pb.dst[t];
    int tilesN = Nn >> 6;
    int tk = local / tilesN, tn = local - tk * tilesN;
    int k0 = tk << 6, n0 = tn << 6;
    int r = tid >> 6, c = tid & 63;
#pragma unroll
    for (int i = 0; i < 16; i++){
      int lk = r * 16 + i;
      T[lk][c] = f2bf(loadf(s, (size_t)(k0 + lk) * Nn + n0 + c, isbf));
    }
    __syncthreads();
#pragma unroll
    for (int i = 0; i < 16; i++){
      int ln = r * 16 + i;
      d[(size_t)(n0 + ln) * ldt + k0 + c] = T[c][ln];
    }
  }
}

// ---------------- ubar_q0: 4-way k-split Q0 + float4 Ubar row ----------------
__global__ __launch_bounds__(256) void ubar_q0(const float* __restrict__ S0,
    const float* __restrict__ Wq0, const float* __restrict__ bq0,
    const float* __restrict__ Wk0, const float* __restrict__ bk0,
    float* __restrict__ Q0, short* __restrict__ Ubart, float* __restrict__ cvec)
{
  __shared__ float part[256];
  __shared__ float q0s[64];
  int j = blockIdx.x, h = j / 25, q = j - h * 25;
  int tid = threadIdx.x;
  // Q0 slice via 4-way k-split (all 256 threads active)
  {
    int c = tid & 63, kq = tid >> 6;
    const float* s0 = S0 + q * 256 + kq * 64;
    const float* wq = Wq0 + (size_t)(kq * 64) * 256 + h * 64 + c;
    float a = 0.f;
#pragma unroll
    for (int e = 0; e < 64; e++) a = fmaf(s0[e], wq[(size_t)e * 256], a);
    part[kq * 64 + c] = a;
  }
  __syncthreads();
  if (tid < 64){
    int c = h * 64 + tid;
    float acc = bq0[c] + part[tid] + part[64 + tid] + part[128 + tid] + part[192 + tid];
    q0s[tid] = acc;
    Q0[q * 256 + c] = acc;
  }
  __syncthreads();
  float acc = 0.f;
  const float* wp = &Wk0[(size_t)tid * 256 + h * 64];
#pragma unroll
  for (int d = 0; d < 64; d += 4){
    float4 w4 = *reinterpret_cast<const float4*>(wp + d);
    float4 q4 = *reinterpret_cast<const float4*>(&q0s[d]);
    acc = fmaf(w4.x, q4.x, acc); acc = fmaf(w4.y, q4.y, acc);
    acc = fmaf(w4.z, q4.z, acc); acc = fmaf(w4.w, q4.w, acc);
  }
  Ubart[(size_t)j * 264 + tid] = f2bf(acc * 0.0625f);
  if (tid == 0){
    float cb = 0.f;
    for (int d = 0; d < 64; d++) cb = fmaf(bk0[h * 64 + d], q0s[d], cb);
    cvec[j] = cb * 0.0625f;
  }
}

// ---------------- gcn_tail: GCN + fused VdS-GEMM + attention tail, per graph ------
// R7 structure + lgkm-only barriers (prefetched global loads now genuinely span barriers).
struct GTParams {
  const void* X;
  const float* Adj;
  const short* W1t; const float* b1;
  const short* W2t; const float* b2;
  float* p1; float* p2;
  const short* Wv0t;   // [256][264]
  const short* Ubart;  // [100][264] (pre-scaled 1/16)
  const float* biasVS; // [bv0(256) | cvec(100)]
  const float* Q0;
  const short* Wo0t;  const float* bo0;
  const short* WQKVt; const float* biasQKV;
  const short* Wo1t;  const float* bo1;
  const float *S2w, *Wq2, *bq2, *Wv2, *bv2, *Wo2, *bo2, *Wl, *bl, *Wc1, *bc1, *Wc2, *bc2, *Wc3, *bc3;
  float* out;
};

__global__ __launch_bounds__(512) void gcn_tail(GTParams P)
{
  __shared__ __align__(16) char pool[162880];
  __shared__ float dinvL[112];
  __shared__ int flagS;
  // gcn aliases
  short* S1x = (short*)(pool);            // X-stage, then x1 A-layout
  short* S2b = (short*)(pool + 30464);
  short* S4b = (short*)(pool + 65280);
  short* Asb = (short*)(pool + 100096);
  float* AdjL = (float*)(pool + 30464);   // raw counts [100][100] f32; dead before p1 writes S2b
  // tail region bases
  char* R1 = pool;
  char* RV = pool + 57344;
  char* RS = pool + 122880;
  float* Ssh  = (float*)RS;            // [100][100]
  short* Pbf  = (short*)R1;            // [4][32][136]
  short* Abf  = (short*)(R1 + 34816);  // [32][264]
  float* hva  = (float*)(R1 + 51712);
  float* hvb  = (float*)(R1 + 52224);
  float* O1F  = (float*)R1;            // [25][132]
  float* OaF  = (float*)RS;            // [25][260]
  float* ObF  = (float*)RS;            // [25][132]
  short* Abf2 = (short*)(RS + 26000);  // [32][136]
  float* QKV  = (float*)RV;            // [25][388]
  float* Ss2  = (float*)(RV + 38800);  // [4][25][26]
  float* hpart= (float*)(RV + 38800);

  int g = blockIdx.x, tid = threadIdx.x;
  bool isbf = block_sniff(P.X, tid, &flagS);
  int wave = tid >> 6, lane = tid & 63, quad = lane >> 4, l16 = lane & 15;
  int gn = wave * 16 + l16;

  // prefetch W1/W2 B-frags at t=0 (consumed p1 / p4; loads now survive the barriers)
  s16x8 w1f[4], w2f[4];
#pragma unroll
  for (int kt = 0; kt < 4; kt++){
    int kb = kt * 32 + quad * 8;
    w1f[kt] = *reinterpret_cast<const s16x8*>(P.W1t + (size_t)gn * 136 + kb);
    w2f[kt] = *reinterpret_cast<const s16x8*>(P.W2t + (size_t)gn * 136 + kb);
  }

  // P0: zero whole pool once (all stale-LDS hazards die here)
  for (int i = tid; i < 162880 / 4; i += 512) ((int*)pool)[i] = 0;
  barrier_lds();

  // P1: coalesced stage of raw Adj counts + X
  {
    const float* Ag = P.Adj + (size_t)g * (MAXN * MAXN);
    for (int i = tid; i < 2500; i += 512)
      ((float4*)AdjL)[i] = ((const float4*)Ag)[i];
  }
  for (int i = tid; i < MAXN * 16; i += 512){
    int r = i >> 4, k8 = (i & 15) << 3;
    s16x8 v;
    if (isbf){
      v = *reinterpret_cast<const s16x8*>((const short*)P.X + (size_t)(g * MAXN + r) * 128 + k8);
    } else {
      const float* ap = (const float*)P.X + (size_t)(g * MAXN + r) * 128 + k8;
      float4 f0 = *reinterpret_cast<const float4*>(ap);
      float4 f1 = *reinterpret_cast<const float4*>(ap + 4);
      v[0] = f2bf(f0.x); v[1] = f2bf(f0.y); v[2] = f2bf(f0.z); v[3] = f2bf(f0.w);
      v[4] = f2bf(f1.x); v[5] = f2bf(f1.y); v[6] = f2bf(f1.z); v[7] = f2bf(f1.w);
    }
    *reinterpret_cast<s16x8*>(&S1x[r * GLDK + k8]) = v;
  }
  barrier_lds();

  // P2: deg[r] = 1 + rowsum (from LDS); 4 lanes/row + shfl reduce
  if (tid < 400){
    int r = tid >> 2, j0 = (tid & 3) * 25;
    const float* row = AdjL + r * 100 + j0;
    float s = 0.f;
#pragma unroll
    for (int j = 0; j < 25; j++) s += row[j];
    s += __shfl_xor(s, 1); s += __shfl_xor(s, 2);
    if ((tid & 3) == 0) dinvL[r] = rsqrtf(1.0f + s);
  }
  barrier_lds();

  // P3: normalize (LDS->LDS): Asb = (cnt + I) * dinv[r]*dinv[s]
  for (int i = tid; i < MAXN * MAXN; i += 512){
    int r = i / MAXN, s = i - r * MAXN;
    float v = AdjL[i] + (r == s ? 1.0f : 0.0f);
    Asb[r * GLDK + s] = f2bf(v * dinvL[r] * dinvL[s]);
  }
  barrier_lds();

  f32x4 acc[7];
  auto zacc = [&](){
#pragma unroll
    for (int rt = 0; rt < 7; rt++) acc[rt] = (f32x4){0.f,0.f,0.f,0.f};
  };
  auto passL = [&](const short* Abuf, const short* Bbuf){
#pragma unroll
    for (int kt = 0; kt < 4; kt++){
      int kb = kt * 32 + quad * 8;
      s16x8 bf0 = *reinterpret_cast<const s16x8*>(&Bbuf[gn * GLDK + kb]);
#pragma unroll
      for (int rt = 0; rt < 7; rt++){
        s16x8 a = *reinterpret_cast<const s16x8*>(&Abuf[(rt * 16 + l16) * GLDK + kb]);
        acc[rt] = __builtin_amdgcn_mfma_f32_16x16x32_bf16(a, bf0, acc[rt], 0, 0, 0);
      }
    }
  };
  auto passGF = [&](const short* Abuf, const s16x8* bfr){
#pragma unroll
    for (int kt = 0; kt < 4; kt++){
      int kb = kt * 32 + quad * 8;
#pragma unroll
      for (int rt = 0; rt < 7; rt++){
        s16x8 a = *reinterpret_cast<const s16x8*>(&Abuf[(rt * 16 + l16) * GLDK + kb]);
        acc[rt] = __builtin_amdgcn_mfma_f32_16x16x32_bf16(a, bfr[kt], acc[rt], 0, 0, 0);
      }
    }
  };
  auto writeB = [&](short* Bbuf){
#pragma unroll
    for (int rt = 0; rt < 7; rt++){
      short4 o;
      o.x = f2bf(acc[rt][0]); o.y = f2bf(acc[rt][1]);
      o.z = f2bf(acc[rt][2]); o.w = f2bf(acc[rt][3]);
      *reinterpret_cast<short4*>(&Bbuf[gn * GLDK + rt * 16 + quad * 4]) = o;
    }
  };
  float s1sum = 0.f, s2sum = 0.f;
  auto hopEpi = [&](const float* bias, short* AoutA, short* BoutB, float& sum){
    float bv = bias[gn];
#pragma unroll
    for (int rt = 0; rt < 7; rt++){
      float vals[4];
#pragma unroll
      for (int r = 0; r < 4; r++){
        int row = rt * 16 + quad * 4 + r;
        float v = fmaxf(acc[rt][r] + bv, 0.f);
        vals[r] = v;
        if (row < MAXN) sum += v;
      }
      short4 o;
      o.x = f2bf(vals[0]); o.y = f2bf(vals[1]); o.z = f2bf(vals[2]); o.w = f2bf(vals[3]);
      *reinterpret_cast<short4*>(&BoutB[gn * GLDK + rt * 16 + quad * 4]) = o;
      if (AoutA){
        AoutA[(rt * 16 + quad * 4 + 0) * GLDK + gn] = o.x;
        AoutA[(rt * 16 + quad * 4 + 1) * GLDK + gn] = o.y;
        AoutA[(rt * 16 + quad * 4 + 2) * GLDK + gn] = o.z;
        AoutA[(rt * 16 + quad * 4 + 3) * GLDK + gn] = o.w;
      }
    }
  };

  // p1: S2 = X@W1
  zacc(); passGF(S1x, w1f); writeB(S2b);
  barrier_lds();
  // p2: x1 = relu(A·S2 + b1) -> S4 (B^T) + S1x (A-layout)
  zacc(); passL(Asb, S2b); hopEpi(P.b1, S1x, S4b, s1sum);
  barrier_lds();
  // p3: xagg cols 0..127 = A·x1 -> stash in regs
  short4 xag0[7];
  zacc(); passL(Asb, S4b);
#pragma unroll
  for (int rt = 0; rt < 7; rt++){
    xag0[rt].x = f2bf(acc[rt][0]); xag0[rt].y = f2bf(acc[rt][1]);
    xag0[rt].z = f2bf(acc[rt][2]); xag0[rt].w = f2bf(acc[rt][3]);
  }
  // p4: S2 = x1@W2 (no barrier: reads S1x, writes S2b; prior S2b reads done pre-p3-barrier)
  zacc(); passGF(S1x, w2f); writeB(S2b);
  barrier_lds();
  // p5: x2 = relu(A·S2 + b2) -> S4
  zacc(); passL(Asb, S2b); hopEpi(P.b2, nullptr, S4b, s2sum);
  barrier_lds();
  // p6: xagg cols 128..255 = A·x2 (stays in acc)
  zacc(); passL(Asb, S4b);

  // prefetch T1 weights (Wv0/Ubar); loads stay in flight across the next 2 barriers
  s16x8 wvf[2][8], ubf[8];
  {
#pragma unroll
    for (int cg = 0; cg < 2; cg++){
      int c = wave * 32 + cg * 16 + l16;
      const short* bw = P.Wv0t + (size_t)c * 264;
#pragma unroll
      for (int kt = 0; kt < 8; kt++) wvf[cg][kt] = *reinterpret_cast<const s16x8*>(bw + kt * 32 + quad * 8);
    }
    int jj = (wave < 7) ? (wave * 16 + l16) : l16;
    const short* bw = P.Ubart + (size_t)jj * 264;
#pragma unroll
    for (int kt = 0; kt < 8; kt++) ubf[kt] = *reinterpret_cast<const s16x8*>(bw + kt * 32 + quad * 8);
  }

  s1sum += __shfl_xor(s1sum, 16); s1sum += __shfl_xor(s1sum, 32);
  s2sum += __shfl_xor(s2sum, 16); s2sum += __shfl_xor(s2sum, 32);
  if (quad == 0){
    P.p1[g * 128 + gn] = s1sum;
    P.p2[g * 128 + gn] = s2sum;
  }
  barrier_lds();   // all p6 reads of Asb/S4b done before pool reuse

  // write xagg (both halves) into R1 swizzled; zero rows 100..111
  {
    short v0[4];
#pragma unroll
    for (int rt = 0; rt < 7; rt++){
      v0[0] = xag0[rt].x; v0[1] = xag0[rt].y; v0[2] = xag0[rt].z; v0[3] = xag0[rt].w;
#pragma unroll
      for (int r = 0; r < 4; r++){
        int node = rt * 16 + quad * 4 + r;
        if (node < MAXN){
          int sw = (node & 7) << 4;
          *(short*)(R1 + ((node * 512 + gn * 2) ^ sw)) = v0[r];
          *(short*)(R1 + ((node * 512 + (gn + 128) * 2) ^ sw)) = f2bf(acc[rt][r]);
        }
      }
    }
    for (int i = tid; i < 1536; i += 512) ((int*)(R1 + 51200))[i] = 0;
  }
  barrier_lds();

  // ---- T1: fused GEMMs on xagg: V = xagg@Wv0 -> VT (swz), S = xagg@Ubar^T -> Ssh ----
  {
#pragma unroll
    for (int cg = 0; cg < 2; cg++){
      int c = wave * 32 + cg * 16 + l16;
      f32x4 vac[7];
#pragma unroll
      for (int rt = 0; rt < 7; rt++) vac[rt] = (f32x4){0.f,0.f,0.f,0.f};
#pragma unroll
      for (int kt = 0; kt < 8; kt++){
        int kb = kt * 32 + quad * 8;
#pragma unroll
        for (int rt = 0; rt < 7; rt++){
          int row = rt * 16 + l16;
          int ab = (row * 512 + kb * 2) ^ ((row & 7) << 4);
          s16x8 a = *reinterpret_cast<const s16x8*>(R1 + ab);
          vac[rt] = __builtin_amdgcn_mfma_f32_16x16x32_bf16(a, wvf[cg][kt], vac[rt], 0, 0, 0);
        }
      }
      float bv = P.biasVS[c];
#pragma unroll
      for (int rt = 0; rt < 7; rt++){
        int node0 = rt * 16 + quad * 4;
        short4 o;
        o.x = f2bf(vac[rt][0] + bv); o.y = f2bf(vac[rt][1] + bv);
        o.z = f2bf(vac[rt][2] + bv); o.w = f2bf(vac[rt][3] + bv);
        int b = (c * 256 + node0 * 2) ^ ((c & 7) << 4);
        *reinterpret_cast<short4*>(RV + b) = o;
      }
    }
    if (wave < 7){
      int j = wave * 16 + l16;
      f32x4 sac[7];
#pragma unroll
      for (int rt = 0; rt < 7; rt++) sac[rt] = (f32x4){0.f,0.f,0.f,0.f};
#pragma unroll
      for (int kt = 0; kt < 8; kt++){
        int kb = kt * 32 + quad * 8;
#pragma unroll
        for (int rt = 0; rt < 7; rt++){
          int row = rt * 16 + l16;
          int ab = (row * 512 + kb * 2) ^ ((row & 7) << 4);
          s16x8 a = *reinterpret_cast<const s16x8*>(R1 + ab);
          sac[rt] = __builtin_amdgcn_mfma_f32_16x16x32_bf16(a, ubf[kt], sac[rt], 0, 0, 0);
        }
      }
      if (j < 100){
        float cv = P.biasVS[256 + j];
#pragma unroll
        for (int rt = 0; rt < 7; rt++){
#pragma unroll
          for (int r = 0; r < 4; r++){
            int node = rt * 16 + quad * 4 + r;
            if (node < MAXN) Ssh[node * 100 + j] = sac[rt][r] + cv;
          }
        }
      }
    }
  }
  barrier_lds();

  // ---- T2: fused softmax+transpose -> Pbf; spare threads zero Pbf k in [100,128) ----
  if (tid < 400){
    int k = tid >> 2, h = tid & 3;
    const float* base = &Ssh[k * 100 + h * 25];
    float v[25];
    float m = -1e30f;
#pragma unroll
    for (int q = 0; q < 25; q++){ v[q] = base[q]; m = fmaxf(m, v[q]); }
    float s = 0.f;
#pragma unroll
    for (int q = 0; q < 25; q++){ float e = __expf(v[q] - m); v[q] = e; s += e; }
    float inv = 1.0f / s;
    short* pb = &Pbf[h * 32 * 136 + k];
#pragma unroll
    for (int q = 0; q < 25; q++) pb[q * 136] = f2bf(v[q] * inv);
  } else {
    for (int idx = tid - 400; idx < 1400; idx += 112){
      int r = idx / 14, c = idx - r * 14;
      int h = r / 25, q = r - h * 25;
      ((int*)Pbf)[(h * 32 + q) * 68 + 50 + c] = 0;
    }
  }
  barrier_lds();

  // ---- T3: AV via MFMA; B-frags from swizzled VT ----
  {
    int h = wave >> 1;
    int cbase = wave * 32;
    f32x4 aac[2][2];
#pragma unroll
    for (int rt = 0; rt < 2; rt++){ aac[rt][0] = (f32x4){0.f,0.f,0.f,0.f}; aac[rt][1] = aac[rt][0]; }
#pragma unroll
    for (int kt = 0; kt < 4; kt++){
      int kb = kt * 32 + quad * 8;
      int c0 = cbase + l16, c1 = cbase + 16 + l16;
      int b0 = (c0 * 256 + kb * 2) ^ ((c0 & 7) << 4);
      int b1 = (c1 * 256 + kb * 2) ^ ((c1 & 7) << 4);
      s16x8 vb0 = *reinterpret_cast<const s16x8*>(RV + b0);
      s16x8 vb1 = *reinterpret_cast<const s16x8*>(RV + b1);
#pragma unroll
      for (int rt = 0; rt < 2; rt++){
        s16x8 a = *reinterpret_cast<const s16x8*>(&Pbf[(h * 32 + rt * 16 + l16) * 136 + kb]);
        aac[rt][0] = __builtin_amdgcn_mfma_f32_16x16x32_bf16(a, vb0, aac[rt][0], 0, 0, 0);
        aac[rt][1] = __builtin_amdgcn_mfma_f32_16x16x32_bf16(a, vb1, aac[rt][1], 0, 0, 0);
      }
    }
    // prefetch Wo0 B-frags (consumed next phase; loads span the barrier)
    s16x8 o0f0[8], o0f1[8];
    {
      int c0w = wave * 16 + l16, c1w = c0w + 128;
#pragma unroll
      for (int kt = 0; kt < 8; kt++){
        int kb = kt * 32 + quad * 8;
        o0f0[kt] = *reinterpret_cast<const s16x8*>(&P.Wo0t[(size_t)c0w * 264 + kb]);
        o0f1[kt] = *reinterpret_cast<const s16x8*>(&P.Wo0t[(size_t)c1w * 264 + kb]);
      }
    }
#pragma unroll
    for (int cg = 0; cg < 2; cg++){
      int c = cbase + cg * 16 + l16;
#pragma unroll
      for (int rt = 0; rt < 2; rt++){
#pragma unroll
        for (int r = 0; r < 4; r++){
          int row = rt * 16 + quad * 4 + r;
          if (row < 25){
            float oa = aac[rt][cg][r] + P.Q0[row * 256 + c];
            OaF[row * 260 + c] = oa;
            Abf[row * 264 + c] = f2bf(oa);
          }
        }
      }
    }
    barrier_lds();

    // Wo0 (B-frags prefetched)
    {
      int c0 = wave * 16 + l16, c1 = c0 + 128;
      f32x4 a0[2], a1[2];
#pragma unroll
      for (int rt = 0; rt < 2; rt++){ a0[rt] = (f32x4){0.f,0.f,0.f,0.f}; a1[rt] = a0[rt]; }
#pragma unroll
      for (int kt = 0; kt < 8; kt++){
        int kb = kt * 32 + quad * 8;
#pragma unroll
        for (int rt = 0; rt < 2; rt++){
          s16x8 a = *reinterpret_cast<const s16x8*>(&Abf[(rt * 16 + l16) * 264 + kb]);
          a0[rt] = __builtin_amdgcn_mfma_f32_16x16x32_bf16(a, o0f0[kt], a0[rt], 0, 0, 0);
          a1[rt] = __builtin_amdgcn_mfma_f32_16x16x32_bf16(a, o0f1[kt], a1[rt], 0, 0, 0);
        }
      }
      barrier_lds();
#pragma unroll
      for (int cg = 0; cg < 2; cg++){
        int col = cg ? c1 : c0;
        float bv = P.bo0[col];
#pragma unroll
        for (int rt = 0; rt < 2; rt++){
          f32x4 av = cg ? a1[rt] : a0[rt];
#pragma unroll
          for (int r = 0; r < 4; r++){
            int row = rt * 16 + quad * 4 + r;
            if (row < 25){
              float t = av[r] + bv;
              Abf[row * 264 + col] = f2bf(OaF[row * 260 + col] + fmaxf(t, 0.f));
            }
          }
        }
      }
    }
  }
  // prefetch QKV B-frags (consumed next phase; loads span the barrier)
  s16x8 qkvf[3][8];
  {
    int c0 = wave * 16 + l16;
#pragma unroll
    for (int p2 = 0; p2 < 3; p2++)
#pragma unroll
      for (int kt = 0; kt < 8; kt++){
        int kb = kt * 32 + quad * 8;
        qkvf[p2][kt] = *reinterpret_cast<const s16x8*>(&P.WQKVt[(size_t)(c0 + p2 * 128) * 264 + kb]);
      }
  }
  barrier_lds();

  // QKV (B-frags prefetched)
  {
    int c0 = wave * 16 + l16;
    f32x4 qac[3][2];
#pragma unroll
    for (int p2 = 0; p2 < 3; p2++)
#pragma unroll
      for (int rt = 0; rt < 2; rt++) qac[p2][rt] = (f32x4){0.f,0.f,0.f,0.f};
#pragma unroll
    for (int kt = 0; kt < 8; kt++){
      int kb = kt * 32 + quad * 8;
#pragma unroll
      for (int rt = 0; rt < 2; rt++){
        s16x8 a = *reinterpret_cast<const s16x8*>(&Abf[(rt * 16 + l16) * 264 + kb]);
#pragma unroll
        for (int p2 = 0; p2 < 3; p2++)
          qac[p2][rt] = __builtin_amdgcn_mfma_f32_16x16x32_bf16(a, qkvf[p2][kt], qac[p2][rt], 0, 0, 0);
      }
    }
#pragma unroll
    for (int p2 = 0; p2 < 3; p2++){
      int col = c0 + p2 * 128;
      float bv = P.biasQKV[col];
#pragma unroll
      for (int rt = 0; rt < 2; rt++){
#pragma unroll
        for (int r = 0; r < 4; r++){
          int row = rt * 16 + quad * 4 + r;
          if (row < 25) QKV[row * 388 + col] = qac[p2][rt][r] + bv;
        }
      }
    }
  }
  barrier_lds();

  // SAB scores
  for (int idx = tid; idx < 2500; idx += 512){
    int h = idx / 625;
    int r = idx - h * 625;
    int q = r / 25, k = r - q * 25;
    const float* qp = &QKV[q * 388 + h * 32];
    const float* kp = &QKV[k * 388 + 128 + h * 32];
    float sac = 0.f;
#pragma unroll
    for (int d = 0; d < 32; d += 4){
      float4 a4 = *reinterpret_cast<const float4*>(&qp[d]);
      float4 b4 = *reinterpret_cast<const float4*>(&kp[d]);
      sac = fmaf(a4.x, b4.x, sac); sac = fmaf(a4.y, b4.y, sac);
      sac = fmaf(a4.z, b4.z, sac); sac = fmaf(a4.w, b4.w, sac);
    }
    Ss2[(h * 25 + q) * 26 + k] = sac * 0.0883883476f;
  }
  barrier_lds();
  if (tid < 100){
    int h = tid / 25, k = tid - h * 25;
    float m = -1e30f;
#pragma unroll
    for (int q = 0; q < 25; q++) m = fmaxf(m, Ss2[(h * 25 + q) * 26 + k]);
    float s = 0.f;
#pragma unroll
    for (int q = 0; q < 25; q++){ float e = __expf(Ss2[(h * 25 + q) * 26 + k] - m); Ss2[(h * 25 + q) * 26 + k] = e; s += e; }
    float inv = 1.0f / s;
#pragma unroll
    for (int q = 0; q < 25; q++) Ss2[(h * 25 + q) * 26 + k] *= inv;
  }
  barrier_lds();

  // Ob = Q1 + AV, q-split across tid<256
  if (tid < 256){
    int qh = tid >> 7;
    int c = tid & 127, h = c >> 5;
    int q0 = qh * 13, nq = 13 - qh;
    float oac[13] = {};
    for (int k = 0; k < 25; k++){
      float v = QKV[k * 388 + 256 + c];
      for (int j = 0; j < nq; j++)
        oac[j] = fmaf(Ss2[(h * 25 + q0 + j) * 26 + k], v, oac[j]);
    }
    for (int j = 0; j < nq; j++){
      int q = q0 + j;
      float ob = QKV[q * 388 + c] + oac[j];
      ObF[q * 132 + c] = ob;
      Abf2[q * 136 + c] = f2bf(ob);
    }
  }
  // prefetch Wo1 B-frags (consumed next phase; loads span the barrier)
  s16x8 o1f[4];
  {
    int c0 = wave * 16 + l16;
#pragma unroll
    for (int kt = 0; kt < 4; kt++){
      int kb = kt * 32 + quad * 8;
      o1f[kt] = *reinterpret_cast<const s16x8*>(&P.Wo1t[(size_t)c0 * 136 + kb]);
    }
  }
  barrier_lds();

  // O1 = Ob + relu(Ob @ Wo1 + bo1)
  {
    int c0 = wave * 16 + l16;
    f32x4 a0 = (f32x4){0.f,0.f,0.f,0.f}, a1 = a0;
#pragma unroll
    for (int kt = 0; kt < 4; kt++){
      int kb = kt * 32 + quad * 8;
      s16x8 aA = *reinterpret_cast<const s16x8*>(&Abf2[l16 * 136 + kb]);
      s16x8 aB = *reinterpret_cast<const s16x8*>(&Abf2[(16 + l16) * 136 + kb]);
      a0 = __builtin_amdgcn_mfma_f32_16x16x32_bf16(aA, o1f[kt], a0, 0, 0, 0);
      a1 = __builtin_amdgcn_mfma_f32_16x16x32_bf16(aB, o1f[kt], a1, 0, 0, 0);
    }
    float bv = P.bo1[c0];
#pragma unroll
    for (int r = 0; r < 4; r++){
      int row0 = quad * 4 + r;
      if (row0 < 25){ float t = a0[r] + bv; O1F[row0 * 132 + c0] = ObF[row0 * 132 + c0] + fmaxf(t, 0.f); }
      int row1 = 16 + quad * 4 + r;
      if (row1 < 25){ float t = a1[r] + bv; O1F[row1 * 132 + c0] = ObF[row1 * 132 + c0] + fmaxf(t, 0.f); }
    }
  }
  barrier_lds();

  // head: colsum then 4-way k-split matvec chain
  if (tid < 128){
    float s = 0.f;
    for (int k = 0; k < 25; k++) s += O1F[k * 132 + tid];
    hva[tid] = s;
  }
  barrier_lds();
  {
    int kh = tid >> 7, c = tid & 127, k0 = kh * 32;
    float s = 0.f;
    for (int k = k0; k < k0 + 32; k++)
      s = fmaf(P.S2w[k], P.Wq2[k * 128 + c], fmaf(hva[k], P.Wv2[k * 128 + c], s));
    hpart[kh * 128 + c] = s;
    barrier_lds();
    if (tid < 128) hvb[c] = hpart[c] + hpart[128 + c] + hpart[256 + c] + hpart[384 + c]
                          + P.bq2[c] + 25.f * P.bv2[c];
    barrier_lds();
    s = 0.f;
    for (int k = k0; k < k0 + 32; k++) s = fmaf(hvb[k], P.Wo2[k * 128 + c], s);
    hpart[kh * 128 + c] = s;
    barrier_lds();
    if (tid < 128) hva[c] = hvb[c] + fmaxf(hpart[c] + hpart[128 + c] + hpart[256 + c] + hpart[384 + c] + P.bo2[c], 0.f);
    barrier_lds();
    s = 0.f;
    for (int k = k0; k < k0 + 32; k++) s = fmaf(hva[k], P.Wl[k * 128 + c], s);
    hpart[kh * 128 + c] = s;
    barrier_lds();
    if (tid < 128) hvb[c] = hpart[c] + hpart[128 + c] + hpart[256 + c] + hpart[384 + c] + P.bl[c];
    barrier_lds();
    s = 0.f;
    for (int k = k0; k < k0 + 32; k++) s = fmaf(hvb[k], P.Wc1[k * 128 + c], s);
    hpart[kh * 128 + c] = s;
    barrier_lds();
    if (tid < 128) hva[c] = fmaxf(hpart[c] + hpart[128 + c] + hpart[256 + c] + hpart[384 + c] + P.bc1[c], 0.f);
    barrier_lds();
    {
      int kh2 = tid >> 6, c2 = tid & 63, kk0 = kh2 * 16;
      float s2 = 0.f;
      for (int k = kk0; k < kk0 + 16; k++) s2 = fmaf(hva[k], P.Wc2[k * 64 + c2], s2);
      hpart[kh2 * 64 + c2] = s2;
    }
    barrier_lds();
    if (tid < 64){
      float s2 = hpart[tid] + hpart[64 + tid] + hpart[128 + tid] + hpart[192 + tid]
               + hpart[256 + tid] + hpart[320 + tid] + hpart[384 + tid] + hpart[448 + tid];
      hvb[tid] = fmaxf(s2 + P.bc2[tid], 0.f);
    }
    barrier_lds();
    if (tid < 10){
      float lg = P.bc3[tid];
      for (int k = 0; k < 64; k++) lg = fmaf(hvb[k], P.Wc3[k * 10 + tid], lg);
      P.out[g * 10 + tid] = lg;
    }
  }
}

// ---------------- host ----------------
extern "C" void kernel_launch(void* const* d_in, const int* in_sizes, int n_in,
                              void* d_out, int out_size, void* d_ws, size_t ws_size,
                              hipStream_t stream)
{
  const int*  edge = (const int*)d_in[1];
  const int N = in_sizes[0] / FIN;      // 20000
  const int E = in_sizes[1] / 2;        // 320000
  const int G = N / MAXN;               // 200
  const int* srcp = edge;
  const int* dstp = edge + E;
  float* out = (float*)d_out;           // f32: [logits 200x10 | p1 200x128 | p2 200x128]

  float* w = (float*)d_ws;
  size_t off = 0;
  auto alloc = [&](size_t nfl){ nfl = (nfl + 3) & ~(size_t)3; float* p = w + off; off += nfl; return p; };
  auto allocS = [&](size_t nsh)->short*{ size_t nfl = ((nsh + 1) / 2 + 3) & ~(size_t)3; short* p = (short*)(w + off); off += nfl; return p; };

  float* biasVS  = alloc(356);          // [bv0 | cvec]
  float* biasQKV = alloc(384);          // [bq1 | bk1 | bv1]
  float* cvec = biasVS + 256;

  const int castT[24] = {4,6,7,8,9,10,11,15,23,24,25,26,29,30,31,32,33,34,35,36,37,38,39,40};
  float* wf[41] = {nullptr};
  for (int i = 0; i < 24; i++) wf[castT[i]] = alloc((size_t)in_sizes[castT[i]]);
  wf[13] = biasVS; wf[17] = biasQKV; wf[19] = biasQKV + 128; wf[21] = biasQKV + 256;

  float* Adj = alloc((size_t)G * MAXN * MAXN);     // unnormalized counts
  float* Q0  = alloc(25 * 256);

  short* W1t   = allocS(128 * 136);
  short* W2t   = allocS(128 * 136);
  short* WVSt  = allocS(356 * 264);     // [Wv0t | Ubart]
  short* WQKVt = allocS(384 * 264);     // [Wq1t | Wk1t | Wv1t]
  short* Wo0t  = allocS(256 * 264);
  short* Wo1t  = allocS(128 * 136);
  short* Ubart = WVSt + (size_t)256 * 264;
  if (off * sizeof(float) > ws_size) return;

  dim3 blk(256);

  // 0. zero Adj via DMA (stream-ordered, graph-capture-legal)
  (void)hipMemsetAsync(Adj, 0, (size_t)G * MAXN * MAXN * sizeof(float), stream);

  // 1. unified prep (inline sniff; casts + tiled transposes + edge atomics)
  PrepBatch pb; int ne = 0, blks = 0;
  pb.xptr = d_in[0];
  auto addC = [&](const void* s, float* d, int n){
    pb.src[ne]=s; pb.dst[ne]=d; pb.a[ne]=n; pb.b[ne]=0; pb.blk0[ne]=blks;
    blks += ceil_div(ceil_div(n, 4), 256); ne++; };
  auto addW = [&](const void* s, short* d, int K, int Nn){
    pb.src[ne]=s; pb.dst[ne]=d; pb.a[ne]=K; pb.b[ne]=Nn; pb.blk0[ne]=blks;
    blks += (K >> 6) * (Nn >> 6); ne++; };
  for (int i = 0; i < 24; i++){ int t = castT[i]; addC(d_in[t], wf[t], in_sizes[t]); }
  addC(d_in[13], biasVS, 256);
  addC(d_in[17], biasQKV, 128); addC(d_in[19], biasQKV + 128, 128); addC(d_in[21], biasQKV + 256, 128);
  addW(d_in[3],  W1t, 128, 128);             addW(d_in[5],  W2t, 128, 128);
  addW(d_in[12], WVSt, 256, 256);            addW(d_in[16], WQKVt, 256, 128);
  addW(d_in[18], WQKVt + 128*264, 256, 128); addW(d_in[20], WQKVt + 256*264, 256, 128);
  addW(d_in[14], Wo0t, 256, 256);            addW(d_in[22], Wo1t, 128, 128);
  pb.blk0[ne] = blks; pb.ne = ne;
  pb.nTaskBlks = blks;
  pb.esrc = srcp; pb.edst = dstp; pb.eadj = Adj; pb.ecnt = E;
  int nEdgeBlks = ceil_div(E, 256);
  prep_all<<<dim3(blks + nEdgeBlks), blk, 0, stream>>>(pb);

  // 2. Q0 + Ubar^T + cvec
  ubar_q0<<<dim3(100), blk, 0, stream>>>(wf[7], wf[8], wf[9], wf[10], wf[11], Q0, Ubart, cvec);

  // 3. fused GCN + tail megakernel (lgkm-only barriers; weight loads span phases)
  GTParams tp;
  tp.X = d_in[0]; tp.Adj = Adj;
  tp.W1t = W1t; tp.b1 = wf[4]; tp.W2t = W2t; tp.b2 = wf[6];
  tp.p1 = out + 2000; tp.p2 = out + 27600;
  tp.Wv0t = WVSt; tp.Ubart = Ubart; tp.biasVS = biasVS;
  tp.Q0 = Q0;
  tp.Wo0t = Wo0t; tp.bo0 = wf[15];
  tp.WQKVt = WQKVt; tp.biasQKV = biasQKV;
  tp.Wo1t = Wo1t; tp.bo1 = wf[23];
  tp.S2w = wf[24]; tp.Wq2 = wf[25]; tp.bq2 = wf[26]; tp.Wv2 = wf[29]; tp.bv2 = wf[30];
  tp.Wo2 = wf[31]; tp.bo2 = wf[32]; tp.Wl = wf[33]; tp.bl = wf[34];
  tp.Wc1 = wf[35]; tp.bc1 = wf[36]; tp.Wc2 = wf[37]; tp.bc2 = wf[38];
  tp.Wc3 = wf[39]; tp.bc3 = wf[40];
  tp.out = out;
  gcn_tail<<<dim3(G), dim3(512), 0, stream>>>(tp);
}